// Round 1
// baseline (1374.080 us; speedup 1.0000x reference)
//
#include <hip/hip_runtime.h>
#include <math.h>

#define D_MODEL 1024
#define NHEAD   16
#define DKH     64
#define SEQ     2048
#define BATCH   2

// ---------------- GEMM: C = A * W^T + bias ----------------
// A: M x 1024 row-major. W: 1024 x 1024 row-major (we dot along its rows).
// 64x64 tile, one wave (64 threads), 8x8 per-thread microtile, BK=16.
__global__ __launch_bounds__(64)
void gemm_nt(const float* __restrict__ A, const float* __restrict__ W,
             const float* __restrict__ bias, float* __restrict__ C,
             int out_qkv)
{
    __shared__ __align__(16) float As[16][68];
    __shared__ __align__(16) float Bs[16][68];
    const int t  = threadIdx.x;
    const int ty = t >> 3, tx = t & 7;
    const int m0 = blockIdx.x * 64, n0 = blockIdx.y * 64;

    float acc[8][8];
#pragma unroll
    for (int i = 0; i < 8; ++i)
#pragma unroll
        for (int j = 0; j < 8; ++j) acc[i][j] = 0.f;

    for (int k0 = 0; k0 < D_MODEL; k0 += 16) {
#pragma unroll
        for (int c = 0; c < 4; ++c) {
            const int i4 = c * 64 + t;        // 0..255
            const int m  = i4 >> 2;           // 0..63
            const int kq = (i4 & 3) << 2;     // 0,4,8,12
            float4 a = *(const float4*)&A[(size_t)(m0 + m) * D_MODEL + k0 + kq];
            As[kq + 0][m] = a.x; As[kq + 1][m] = a.y;
            As[kq + 2][m] = a.z; As[kq + 3][m] = a.w;
            float4 b = *(const float4*)&W[(size_t)(n0 + m) * D_MODEL + k0 + kq];
            Bs[kq + 0][m] = b.x; Bs[kq + 1][m] = b.y;
            Bs[kq + 2][m] = b.z; Bs[kq + 3][m] = b.w;
        }
        __syncthreads();
#pragma unroll
        for (int kk = 0; kk < 16; ++kk) {
            float4 a0 = *(const float4*)&As[kk][ty * 8];
            float4 a1 = *(const float4*)&As[kk][ty * 8 + 4];
            float4 b0 = *(const float4*)&Bs[kk][tx * 8];
            float4 b1 = *(const float4*)&Bs[kk][tx * 8 + 4];
            const float ar[8] = {a0.x,a0.y,a0.z,a0.w,a1.x,a1.y,a1.z,a1.w};
            const float br[8] = {b0.x,b0.y,b0.z,b0.w,b1.x,b1.y,b1.z,b1.w};
#pragma unroll
            for (int i = 0; i < 8; ++i)
#pragma unroll
                for (int j = 0; j < 8; ++j)
                    acc[i][j] += ar[i] * br[j];
        }
        __syncthreads();
    }

#pragma unroll
    for (int i = 0; i < 8; ++i) {
        const int m = m0 + ty * 8 + i;
        const int b = m >> 11, s = m & 2047;   // m = b*SEQ + s
#pragma unroll
        for (int j = 0; j < 8; ++j) {
            const int n = n0 + tx * 8 + j;
            const float val = acc[i][j] + bias[n];
            size_t dst;
            if (out_qkv) {
                const int h = n >> 6, dk = n & 63;
                dst = ((((size_t)b * NHEAD + h) * SEQ + s) << 6) + dk;
            } else {
                dst = (size_t)m * D_MODEL + n;
            }
            C[dst] = val;
        }
    }
}

// ---------------- Attention (flash-style, fp32) ----------------
// grid: B*H*(SEQ/64) blocks of 256 threads (4 waves, 16 q-rows per wave).
// LDS tiles use XOR quad-swizzle: element (row r, dim d) stored at
// r*64 + (d ^ (r & 28)) so both row-reads (scores) and column-ish reads
// (PV) are conflict-light float4s.
__global__ __launch_bounds__(256)
void attn_fwd(const float* __restrict__ q, const float* __restrict__ k,
              const float* __restrict__ v, const int* __restrict__ mask,
              float* __restrict__ ctx)
{
    __shared__ __align__(16) float Qs[64 * 64];
    __shared__ __align__(16) float Ks[64 * 64];
    __shared__ __align__(16) float Vs[64 * 64];
    __shared__ __align__(16) float Ps[4][16][64];

    const int blk  = blockIdx.x;
    const int qt   = blk & 31;            // SEQ/64 = 32 q-tiles
    const int bh   = blk >> 5;            // 0..31
    const int b    = bh >> 4, h = bh & 15;
    const int t    = threadIdx.x;
    const int wave = t >> 6, lane = t & 63;
    const int rg   = lane >> 4;           // row group 0..3
    const int lg   = lane & 15;           // key group (scores) / dim group (PV)

    const size_t bh_off = (size_t)bh * SEQ * DKH;

    // stage Q tile (pre-scaled by 1/sqrt(DK) = 1/8)
#pragma unroll
    for (int c = 0; c < 4; ++c) {
        const int i4 = c * 256 + t;       // 0..1023
        const int r  = i4 >> 4;           // 0..63
        const int dq = (i4 & 15) << 2;    // 0..60
        float4 a = *(const float4*)&q[bh_off + (size_t)(qt * 64 + r) * DKH + dq];
        a.x *= 0.125f; a.y *= 0.125f; a.z *= 0.125f; a.w *= 0.125f;
        *(float4*)&Qs[r * 64 + (dq ^ (r & 28))] = a;
    }

    const int row0 = qt * 64 + wave * 16 + rg * 4;
    int mrow[4];
#pragma unroll
    for (int i = 0; i < 4; ++i) mrow[i] = mask[b * SEQ + row0 + i];

    float m_run[4], l_run[4], acc[4][4];
#pragma unroll
    for (int i = 0; i < 4; ++i) {
        m_run[i] = -1e30f; l_run[i] = 0.f;
#pragma unroll
        for (int j = 0; j < 4; ++j) acc[i][j] = 0.f;
    }

    for (int kt = 0; kt < SEQ / 64; ++kt) {
        __syncthreads();   // previous PV done reading Ks/Vs/Ps
#pragma unroll
        for (int c = 0; c < 4; ++c) {
            const int i4 = c * 256 + t;
            const int r  = i4 >> 4;
            const int dq = (i4 & 15) << 2;
            const size_t g = bh_off + (size_t)(kt * 64 + r) * DKH + dq;
            const int   ls = r * 64 + (dq ^ (r & 28));
            *(float4*)&Ks[ls] = *(const float4*)&k[g];
            *(float4*)&Vs[ls] = *(const float4*)&v[g];
        }
        __syncthreads();

        // ---- scores: rows wave*16+rg*4+i, keys lg*4+j ----
        float sc[4][4];
#pragma unroll
        for (int i = 0; i < 4; ++i)
#pragma unroll
            for (int j = 0; j < 4; ++j) sc[i][j] = 0.f;

#pragma unroll 4
        for (int dq = 0; dq < 64; dq += 4) {
            float4 qv[4], kv[4];
#pragma unroll
            for (int i = 0; i < 4; ++i) {
                const int r = wave * 16 + rg * 4 + i;
                qv[i] = *(const float4*)&Qs[r * 64 + (dq ^ (r & 28))];
            }
#pragma unroll
            for (int j = 0; j < 4; ++j) {
                const int kr = lg * 4 + j;
                kv[j] = *(const float4*)&Ks[kr * 64 + (dq ^ (kr & 28))];
            }
#pragma unroll
            for (int i = 0; i < 4; ++i)
#pragma unroll
                for (int j = 0; j < 4; ++j)
                    sc[i][j] += qv[i].x * kv[j].x + qv[i].y * kv[j].y
                              + qv[i].z * kv[j].z + qv[i].w * kv[j].w;
        }

        // ---- mask + online softmax (stats uniform across each 16-lane group)
        float corr[4];
#pragma unroll
        for (int i = 0; i < 4; ++i) {
            if (mrow[i] == 0) {   // masked query row -> uniform attention
#pragma unroll
                for (int j = 0; j < 4; ++j) sc[i][j] = 0.f;
            }
            float mx = fmaxf(fmaxf(sc[i][0], sc[i][1]), fmaxf(sc[i][2], sc[i][3]));
            mx = fmaxf(mx, __shfl_xor(mx, 1));
            mx = fmaxf(mx, __shfl_xor(mx, 2));
            mx = fmaxf(mx, __shfl_xor(mx, 4));
            mx = fmaxf(mx, __shfl_xor(mx, 8));
            const float mnew = fmaxf(m_run[i], mx);
            corr[i] = __expf(m_run[i] - mnew);
            m_run[i] = mnew;
            float ssum = 0.f;
#pragma unroll
            for (int j = 0; j < 4; ++j) {
                const float p = __expf(sc[i][j] - mnew);
                sc[i][j] = p; ssum += p;
            }
            ssum += __shfl_xor(ssum, 1);
            ssum += __shfl_xor(ssum, 2);
            ssum += __shfl_xor(ssum, 4);
            ssum += __shfl_xor(ssum, 8);
            l_run[i] = l_run[i] * corr[i] + ssum;
        }

        // stage P through LDS (per-wave buffer)
#pragma unroll
        for (int i = 0; i < 4; ++i)
#pragma unroll
            for (int j = 0; j < 4; ++j)
                Ps[wave][rg * 4 + i][lg * 4 + j] = sc[i][j];
        __syncthreads();

        // ---- PV: rows rg*4+i, dims lg*4+jj ----
#pragma unroll
        for (int i = 0; i < 4; ++i)
#pragma unroll
            for (int j = 0; j < 4; ++j) acc[i][j] *= corr[i];

#pragma unroll 4
        for (int kq = 0; kq < 64; kq += 4) {
            float pr[4][4];
#pragma unroll
            for (int i = 0; i < 4; ++i) {
                float4 p4 = *(const float4*)&Ps[wave][rg * 4 + i][kq];
                pr[i][0] = p4.x; pr[i][1] = p4.y; pr[i][2] = p4.z; pr[i][3] = p4.w;
            }
#pragma unroll
            for (int kk = 0; kk < 4; ++kk) {
                const int kr = kq + kk;
                float4 vv = *(const float4*)&Vs[kr * 64 + ((lg * 4) ^ (kr & 28))];
#pragma unroll
                for (int i = 0; i < 4; ++i) {
                    acc[i][0] += pr[i][kk] * vv.x;
                    acc[i][1] += pr[i][kk] * vv.y;
                    acc[i][2] += pr[i][kk] * vv.z;
                    acc[i][3] += pr[i][kk] * vv.w;
                }
            }
        }
    }

    // ---- epilogue: normalize, write ctx in (B,S,D) layout ----
#pragma unroll
    for (int i = 0; i < 4; ++i) {
        const float inv = 1.f / l_run[i];
        const int s = row0 + i;
        float4 o;
        o.x = acc[i][0] * inv; o.y = acc[i][1] * inv;
        o.z = acc[i][2] * inv; o.w = acc[i][3] * inv;
        *(float4*)&ctx[((size_t)(b * SEQ + s)) * D_MODEL + h * DKH + lg * 4] = o;
    }
}

extern "C" void kernel_launch(void* const* d_in, const int* in_sizes, int n_in,
                              void* d_out, int out_size, void* d_ws, size_t ws_size,
                              hipStream_t stream)
{
    const float* x    = (const float*)d_in[0];
    const int*   mask = (const int*)d_in[1];
    const float* wq   = (const float*)d_in[2];
    const float* bq   = (const float*)d_in[3];
    const float* wk   = (const float*)d_in[4];
    const float* bk   = (const float*)d_in[5];
    const float* wv   = (const float*)d_in[6];
    const float* bv   = (const float*)d_in[7];
    const float* wo   = (const float*)d_in[8];
    const float* bo   = (const float*)d_in[9];
    float* out = (float*)d_out;

    float* ws = (float*)d_ws;
    const size_t NQ = (size_t)BATCH * NHEAD * SEQ * DKH; // 4M floats
    float* qb = ws;
    float* kb = ws + NQ;
    float* vb = ws + 2 * NQ;
    float* cb = ws + 3 * NQ;   // ctx in (B,S,D) layout

    dim3 ggrid(4096 / 64, 1024 / 64);
    gemm_nt<<<ggrid, 64, 0, stream>>>(x, wq, bq, qb, 1);
    gemm_nt<<<ggrid, 64, 0, stream>>>(x, wk, bk, kb, 1);
    gemm_nt<<<ggrid, 64, 0, stream>>>(x, wv, bv, vb, 1);
    attn_fwd<<<BATCH * NHEAD * (SEQ / 64), 256, 0, stream>>>(qb, kb, vb, mask, cb);
    gemm_nt<<<ggrid, 64, 0, stream>>>(cb, wo, bo, out, 0);
}

// Round 2
// 408.499 us; speedup vs baseline: 3.3637x; 3.3637x over previous
//
#include <hip/hip_runtime.h>
#include <hip/hip_bf16.h>

#define SEQ 2048
#define DM  1024

typedef __attribute__((ext_vector_type(8))) short frag8;   // 8 bf16 = 4 VGPR (MFMA A/B operand)
typedef __attribute__((ext_vector_type(4))) float f32x4;   // MFMA C/D operand

// round-to-nearest-even fp32 -> bf16
__device__ __forceinline__ ushort f2bf(float x) {
    union { float f; unsigned u; } c; c.f = x;
    unsigned r = (c.u + 0x7FFFu + ((c.u >> 16) & 1u)) >> 16;
    return (ushort)r;
}
__device__ __forceinline__ float bf2f(ushort h) {
    union { unsigned u; float f; } c; c.u = ((unsigned)h) << 16;
    return c.f;
}
// x = hi + lo + O(2^-17 x):  hi = RNE(x), lo = RNE(x - hi)  (x-hi exact in fp32)
__device__ __forceinline__ void split2(float x, ushort& h, ushort& l) {
    h = f2bf(x);
    l = f2bf(x - bf2f(h));
}

// ============================================================================
// GEMM  C = A * B^T + bias   (A: MA x 1024 rows over 'm', B: NB x 1024 rows
// over 'n', both contiguous in k).  Tile 128(m) x 64(n), 2 waves, BK=32,
// bf16x3 MFMA, double-buffered LDS with XOR-(r&7) chunk swizzle.
// MODE 0: Q-proj (A=wq,B=x)  -> Qhi/Qlo [bh][s][dk], scaled by 1/8
// MODE 1: K-proj (A=wk,B=x)  -> Khi/Klo [bh][s][dk]
// MODE 2: V-proj (A=x,B=wv)  -> Vthi/Vtlo [bh][dk][s]   (transposed!)
// MODE 3: O-proj (A=wo,B=ctx)-> out fp32 [b][s][e]
// ============================================================================
template<int MODE>
__global__ __launch_bounds__(128, 1)
void gemm_k(const float* __restrict__ A, const float* __restrict__ B,
            const float* __restrict__ bias,
            ushort* __restrict__ o_hi, ushort* __restrict__ o_lo,
            float* __restrict__ o_f)
{
    __shared__ ushort As[2][128 * 64];   // [row 128][8 chunks of 8 bf16] hi=c0..3, lo=c4..7
    __shared__ ushort Bs[2][64 * 64];

    const int t = threadIdx.x;
    const int w = t >> 6, lane = t & 63;
    const int m0 = blockIdx.x * 128, n0 = blockIdx.y * 64;
    const int srow = t >> 3;     // 0..15: row within each 16-row group
    const int skc  = t & 7;      // which float4 of the 32-k row

    f32x4 acc[4][4];
#pragma unroll
    for (int i = 0; i < 4; ++i)
#pragma unroll
        for (int j = 0; j < 4; ++j) acc[i][j] = f32x4{0.f, 0.f, 0.f, 0.f};

    // convert one float4 (4 consecutive k) and write hi/lo into swizzled LDS
    auto put4 = [&](ushort* dst, int r, float4 v) {
        ushort4 hi, lo;
        split2(v.x, hi.x, lo.x); split2(v.y, hi.y, lo.y);
        split2(v.z, hi.z, lo.z); split2(v.w, hi.w, lo.w);
        const int c = skc >> 1, sub = (skc & 1) * 4;
        *(ushort4*)&dst[r * 64 + (((c    ) ^ (r & 7)) << 3) + sub] = hi;
        *(ushort4*)&dst[r * 64 + (((c + 4) ^ (r & 7)) << 3) + sub] = lo;
    };

    // prologue: stage k0 = 0 into buffer 0
    {
#pragma unroll
        for (int i = 0; i < 8; ++i) {
            const int r = i * 16 + srow;
            put4(As[0], r, *(const float4*)&A[(size_t)(m0 + r) * DM + skc * 4]);
        }
#pragma unroll
        for (int i = 0; i < 4; ++i) {
            const int r = i * 16 + srow;
            put4(Bs[0], r, *(const float4*)&B[(size_t)(n0 + r) * DM + skc * 4]);
        }
    }
    __syncthreads();

    float4 pa[8], pb[4];
    for (int ks = 0; ks < 32; ++ks) {
        const int buf = ks & 1;
        const bool more = (ks + 1 < 32);
        if (more) {               // prefetch next K-tile into regs (hides HBM under MFMA)
            const int k0 = (ks + 1) * 32;
#pragma unroll
            for (int i = 0; i < 8; ++i)
                pa[i] = *(const float4*)&A[(size_t)(m0 + i * 16 + srow) * DM + k0 + skc * 4];
#pragma unroll
            for (int i = 0; i < 4; ++i)
                pb[i] = *(const float4*)&B[(size_t)(n0 + i * 16 + srow) * DM + k0 + skc * 4];
        }

        frag8 ah[4], al[4], bh[4], bl[4];
#pragma unroll
        for (int mi = 0; mi < 4; ++mi) {
            const int r = w * 64 + mi * 16 + (lane & 15);
            const int c = lane >> 4;
            ah[mi] = *(const frag8*)&As[buf][r * 64 + (((c    ) ^ (r & 7)) << 3)];
            al[mi] = *(const frag8*)&As[buf][r * 64 + (((c + 4) ^ (r & 7)) << 3)];
        }
#pragma unroll
        for (int ni = 0; ni < 4; ++ni) {
            const int r = ni * 16 + (lane & 15);
            const int c = lane >> 4;
            bh[ni] = *(const frag8*)&Bs[buf][r * 64 + (((c    ) ^ (r & 7)) << 3)];
            bl[ni] = *(const frag8*)&Bs[buf][r * 64 + (((c + 4) ^ (r & 7)) << 3)];
        }
#pragma unroll
        for (int mi = 0; mi < 4; ++mi)
#pragma unroll
            for (int ni = 0; ni < 4; ++ni) {
                acc[mi][ni] = __builtin_amdgcn_mfma_f32_16x16x32_bf16(ah[mi], bh[ni], acc[mi][ni], 0, 0, 0);
                acc[mi][ni] = __builtin_amdgcn_mfma_f32_16x16x32_bf16(ah[mi], bl[ni], acc[mi][ni], 0, 0, 0);
                acc[mi][ni] = __builtin_amdgcn_mfma_f32_16x16x32_bf16(al[mi], bh[ni], acc[mi][ni], 0, 0, 0);
            }

        if (more) {               // convert prefetched regs -> other buffer
            const int nbuf = buf ^ 1;
#pragma unroll
            for (int i = 0; i < 8; ++i) put4(As[nbuf], i * 16 + srow, pa[i]);
#pragma unroll
            for (int i = 0; i < 4; ++i) put4(Bs[nbuf], i * 16 + srow, pb[i]);
        }
        __syncthreads();
    }

    // epilogue: C row (m) = lane>>4 group, 4 consecutive per reg; col (n) = lane&15
    const float sc = (MODE == 0) ? 0.125f : 1.0f;
#pragma unroll
    for (int mi = 0; mi < 4; ++mi) {
        const int row0 = m0 + w * 64 + mi * 16 + ((lane >> 4) << 2);
#pragma unroll
        for (int ni = 0; ni < 4; ++ni) {
            const int col = n0 + ni * 16 + (lane & 15);
            f32x4 v = acc[mi][ni];
            if (MODE == 0 || MODE == 1) {
                // row=e (4 consec -> 4 consec dk), col=s
                float v0 = (v[0] + bias[row0 + 0]) * sc;
                float v1 = (v[1] + bias[row0 + 1]) * sc;
                float v2 = (v[2] + bias[row0 + 2]) * sc;
                float v3 = (v[3] + bias[row0 + 3]) * sc;
                ushort4 hi, lo;
                split2(v0, hi.x, lo.x); split2(v1, hi.y, lo.y);
                split2(v2, hi.z, lo.z); split2(v3, hi.w, lo.w);
                const int b = col >> 11, sp = col & 2047;
                const int h = row0 >> 6, dk = row0 & 63;
                const size_t off = ((size_t)((b * 16 + h) * SEQ + sp)) * 64 + dk;
                *(ushort4*)&o_hi[off] = hi;
                *(ushort4*)&o_lo[off] = lo;
            } else if (MODE == 2) {
                // row=s (4 consec), col=e -> Vt[bh][dk][s]
                const float bb = bias[col];
                ushort4 hi, lo;
                split2(v[0] + bb, hi.x, lo.x); split2(v[1] + bb, hi.y, lo.y);
                split2(v[2] + bb, hi.z, lo.z); split2(v[3] + bb, hi.w, lo.w);
                const int b = row0 >> 11, sp = row0 & 2047;
                const int h = col >> 6, dk = col & 63;
                const size_t off = ((size_t)((b * 16 + h) * 64 + dk)) * SEQ + sp;
                *(ushort4*)&o_hi[off] = hi;
                *(ushort4*)&o_lo[off] = lo;
            } else {
                // row=e (4 consec), col=s -> out[s][e] fp32 float4
                float4 o;
                o.x = v[0] + bias[row0 + 0];
                o.y = v[1] + bias[row0 + 1];
                o.z = v[2] + bias[row0 + 2];
                o.w = v[3] + bias[row0 + 3];
                *(float4*)&o_f[(size_t)col * DM + row0] = o;
            }
        }
    }
}

// ============================================================================
// Flash attention, bf16x3 MFMA, swapped QK^T (S^T = K*Q^T so P^T is
// reg-local in 4-key runs).  Block = (b,h,qtile 128); 4 waves x 32 q-rows.
// ============================================================================
__global__ __launch_bounds__(256, 2)
void attn_k(const ushort* __restrict__ Qh, const ushort* __restrict__ Ql,
            const ushort* __restrict__ Kh, const ushort* __restrict__ Kl,
            const ushort* __restrict__ Vh, const ushort* __restrict__ Vl,
            const int* __restrict__ mask, float* __restrict__ ctx)
{
    __shared__ ushort Ks[64 * 128];     // [key 64][16 chunks: hi c0..7 | lo c8..15] (dk)
    __shared__ ushort Vs[64 * 128];     // [d 64][16 chunks] (keys)
    __shared__ ushort Ps[4][32 * 128];  // per-wave P^T: [q 32][16 chunks] (keys)

    const int t = threadIdx.x, w = t >> 6, lane = t & 63;
    const int bh = blockIdx.x >> 4, qt = blockIdx.x & 15;
    const int b = bh >> 4, h = bh & 15;
    const int q0 = qt * 128 + w * 32;
    const size_t base = (size_t)bh * SEQ * 64;

    // Q fragments (B-operand): lane holds col q=lane&15, 8 contiguous dk
    frag8 qfh[2][2], qfl[2][2];
#pragma unroll
    for (int nf = 0; nf < 2; ++nf)
#pragma unroll
        for (int kb = 0; kb < 2; ++kb) {
            const size_t off = base + (size_t)(q0 + nf * 16 + (lane & 15)) * 64
                             + kb * 32 + ((lane >> 4) << 3);
            qfh[nf][kb] = *(const frag8*)&Qh[off];
            qfl[nf][kb] = *(const frag8*)&Ql[off];
        }

    int msk[2];
#pragma unroll
    for (int nf = 0; nf < 2; ++nf)
        msk[nf] = mask[b * SEQ + q0 + nf * 16 + (lane & 15)];

    float m_run[2] = {-1e30f, -1e30f}, l_run[2] = {0.f, 0.f};
    f32x4 acc[4][2];
#pragma unroll
    for (int df = 0; df < 4; ++df)
#pragma unroll
        for (int nf = 0; nf < 2; ++nf) acc[df][nf] = f32x4{0.f, 0.f, 0.f, 0.f};

    for (int kt = 0; kt < SEQ / 64; ++kt) {
        __syncthreads();   // previous tile fully consumed
        // ---- stage K and Vt tiles (bf16 pre-split in global) ----
#pragma unroll
        for (int j = 0; j < 4; ++j) {
            const int i = j * 256 + t;          // chunk id 0..1023
            const int r = i >> 4, cc = i & 15;
            const int cl = cc & 7;              // logical chunk within hi/lo half
            const int ph = (cl ^ (r & 7)) + (cc & 8);   // physical chunk (swizzled)
            const size_t ko = base + (size_t)(kt * 64 + r) * 64 + (cl << 3);
            const size_t vo = base + (size_t)r * SEQ + kt * 64 + (cl << 3);
            const ushort* kp = (cc < 8) ? Kh : Kl;
            const ushort* vp = (cc < 8) ? Vh : Vl;
            *(frag8*)&Ks[r * 128 + (ph << 3)] = *(const frag8*)&kp[ko];
            *(frag8*)&Vs[r * 128 + (ph << 3)] = *(const frag8*)&vp[vo];
        }
        __syncthreads();

        // ---- S^T = K * Q^T : C[m=key][n=q] ----
        f32x4 st[4][2];
#pragma unroll
        for (int mf = 0; mf < 4; ++mf)
#pragma unroll
            for (int nf = 0; nf < 2; ++nf) st[mf][nf] = f32x4{0.f, 0.f, 0.f, 0.f};
#pragma unroll
        for (int mf = 0; mf < 4; ++mf) {
            const int r = mf * 16 + (lane & 15);
            const int cb = lane >> 4;
#pragma unroll
            for (int kb = 0; kb < 2; ++kb) {
                const int c = kb * 4 + cb;
                const int p = c ^ (r & 7);
                frag8 kfh = *(const frag8*)&Ks[r * 128 + (p << 3)];
                frag8 kfl = *(const frag8*)&Ks[r * 128 + ((p + 8) << 3)];
#pragma unroll
                for (int nf = 0; nf < 2; ++nf) {
                    st[mf][nf] = __builtin_amdgcn_mfma_f32_16x16x32_bf16(kfh, qfh[nf][kb], st[mf][nf], 0, 0, 0);
                    st[mf][nf] = __builtin_amdgcn_mfma_f32_16x16x32_bf16(kfh, qfl[nf][kb], st[mf][nf], 0, 0, 0);
                    st[mf][nf] = __builtin_amdgcn_mfma_f32_16x16x32_bf16(kfl, qfh[nf][kb], st[mf][nf], 0, 0, 0);
                }
            }
        }

        // ---- online softmax over keys (per q-column) ----
        float corr[2];
#pragma unroll
        for (int nf = 0; nf < 2; ++nf) {
            if (msk[nf] == 0) {     // masked query row: uniform attention
#pragma unroll
                for (int mf = 0; mf < 4; ++mf) st[mf][nf] = f32x4{0.f, 0.f, 0.f, 0.f};
            }
            float mx = -1e30f;
#pragma unroll
            for (int mf = 0; mf < 4; ++mf)
#pragma unroll
                for (int r4 = 0; r4 < 4; ++r4) mx = fmaxf(mx, st[mf][nf][r4]);
            mx = fmaxf(mx, __shfl_xor(mx, 16));
            mx = fmaxf(mx, __shfl_xor(mx, 32));
            const float mnew = fmaxf(m_run[nf], mx);
            corr[nf] = __expf(m_run[nf] - mnew);
            m_run[nf] = mnew;
            float ss = 0.f;
#pragma unroll
            for (int mf = 0; mf < 4; ++mf)
#pragma unroll
                for (int r4 = 0; r4 < 4; ++r4) {
                    const float p = __expf(st[mf][nf][r4] - mnew);
                    st[mf][nf][r4] = p; ss += p;
                }
            ss += __shfl_xor(ss, 16);
            ss += __shfl_xor(ss, 32);
            l_run[nf] = l_run[nf] * corr[nf] + ss;
#pragma unroll
            for (int df = 0; df < 4; ++df)
#pragma unroll
                for (int r4 = 0; r4 < 4; ++r4) acc[df][nf][r4] *= corr[nf];
        }

        // ---- write P^T[q][key] hi/lo into per-wave LDS (packed 4-key runs) ----
#pragma unroll
        for (int nf = 0; nf < 2; ++nf) {
            const int q = nf * 16 + (lane & 15);
#pragma unroll
            for (int mf = 0; mf < 4; ++mf) {
                const int key0 = mf * 16 + ((lane >> 4) << 2);
                ushort4 hi, lo;
                split2(st[mf][nf][0], hi.x, lo.x);
                split2(st[mf][nf][1], hi.y, lo.y);
                split2(st[mf][nf][2], hi.z, lo.z);
                split2(st[mf][nf][3], hi.w, lo.w);
                const int c = key0 >> 3, sub = key0 & 7;
                const int p = c ^ (q & 7);
                *(ushort4*)&Ps[w][q * 128 + (p << 3) + sub] = hi;
                *(ushort4*)&Ps[w][q * 128 + ((p + 8) << 3) + sub] = lo;
            }
        }

        // ---- ctx^T += V^T * P^T : C[m=d][n=q] ----
        frag8 pfh[2][2], pfl[2][2];
#pragma unroll
        for (int nf = 0; nf < 2; ++nf) {
            const int q = nf * 16 + (lane & 15);
            const int cb = lane >> 4;
#pragma unroll
            for (int kb = 0; kb < 2; ++kb) {
                const int c = kb * 4 + cb;
                const int p = c ^ (q & 7);
                pfh[nf][kb] = *(const frag8*)&Ps[w][q * 128 + (p << 3)];
                pfl[nf][kb] = *(const frag8*)&Ps[w][q * 128 + ((p + 8) << 3)];
            }
        }
#pragma unroll
        for (int df = 0; df < 4; ++df) {
            const int r = df * 16 + (lane & 15);
            const int cb = lane >> 4;
#pragma unroll
            for (int kb = 0; kb < 2; ++kb) {
                const int c = kb * 4 + cb;
                const int p = c ^ (r & 7);
                frag8 vfh = *(const frag8*)&Vs[r * 128 + (p << 3)];
                frag8 vfl = *(const frag8*)&Vs[r * 128 + ((p + 8) << 3)];
#pragma unroll
                for (int nf = 0; nf < 2; ++nf) {
                    acc[df][nf] = __builtin_amdgcn_mfma_f32_16x16x32_bf16(vfh, pfh[nf][kb], acc[df][nf], 0, 0, 0);
                    acc[df][nf] = __builtin_amdgcn_mfma_f32_16x16x32_bf16(vfh, pfl[nf][kb], acc[df][nf], 0, 0, 0);
                    acc[df][nf] = __builtin_amdgcn_mfma_f32_16x16x32_bf16(vfl, pfh[nf][kb], acc[df][nf], 0, 0, 0);
                }
            }
        }
    }

    // ---- epilogue: ctx[b][s][h*64+d] fp32 (feeds O-proj as B operand) ----
#pragma unroll
    for (int nf = 0; nf < 2; ++nf) {
        const float inv = 1.0f / l_run[nf];
        const int s = q0 + nf * 16 + (lane & 15);
#pragma unroll
        for (int df = 0; df < 4; ++df) {
            const int e0 = h * 64 + df * 16 + ((lane >> 4) << 2);
            float4 o;
            o.x = acc[df][nf][0] * inv;
            o.y = acc[df][nf][1] * inv;
            o.z = acc[df][nf][2] * inv;
            o.w = acc[df][nf][3] * inv;
            *(float4*)&ctx[(size_t)(b * SEQ + s) * DM + e0] = o;
        }
    }
}

extern "C" void kernel_launch(void* const* d_in, const int* in_sizes, int n_in,
                              void* d_out, int out_size, void* d_ws, size_t ws_size,
                              hipStream_t stream)
{
    const float* x  = (const float*)d_in[0];
    const int* mask = (const int*)d_in[1];
    const float* wq = (const float*)d_in[2];
    const float* bq = (const float*)d_in[3];
    const float* wk = (const float*)d_in[4];
    const float* bk = (const float*)d_in[5];
    const float* wv = (const float*)d_in[6];
    const float* bv = (const float*)d_in[7];
    const float* wo = (const float*)d_in[8];
    const float* bo = (const float*)d_in[9];
    float* out = (float*)d_out;

    const size_t NE = (size_t)2 * 16 * SEQ * 64;   // 4Mi elements per buffer
    ushort* Qh = (ushort*)d_ws;                     // ws usage: 6*8MB + 16MB = 64MB
    ushort* Ql = Qh + NE;
    ushort* Kh = Qh + 2 * NE;
    ushort* Kl = Qh + 3 * NE;
    ushort* Vh = Qh + 4 * NE;
    ushort* Vl = Qh + 5 * NE;
    float* ctx = (float*)(Qh + 6 * NE);

    dim3 gsw(8, 64);    // M=1024 (e), N=4096 (s)
    gemm_k<0><<<gsw, 128, 0, stream>>>(wq, x, bq, Qh, Ql, nullptr);
    gemm_k<1><<<gsw, 128, 0, stream>>>(wk, x, bk, Kh, Kl, nullptr);
    gemm_k<2><<<dim3(32, 16), 128, 0, stream>>>(x, wv, bv, Vh, Vl, nullptr);
    attn_k<<<dim3(512), 256, 0, stream>>>(Qh, Ql, Kh, Kl, Vh, Vl, mask, ctx);
    gemm_k<3><<<gsw, 128, 0, stream>>>(wo, ctx, bo, nullptr, nullptr, out);
}